// Round 1
// baseline (695.284 us; speedup 1.0000x reference)
//
#include <hip/hip_runtime.h>

constexpr int BLOCK = 256;
constexpr int ROWS  = 256;          // rows per block (== BLOCK, 1 row/thread)
constexpr int D     = 512;          // inner dim
constexpr int CHUNK = 32;           // columns per LDS chunk
constexpr int NCH   = D / CHUNK;    // 16 chunks
constexpr int LSTR  = CHUNK + 4;    // 36 floats/row: pad keeps b128 conflict-free-ish & 16B aligned

// ---- 4-qubit state helpers (qubit 0 = MSB of 4-bit index, per jax reshape) ----

template<int BIT>
__device__ __forceinline__ void apply_rx(float* sr, float* si, float theta)
{
    float s, c;
    __sincosf(0.5f * theta, &s, &c);
    // gate [[c, -i s],[-i s, c]]
    #pragma unroll
    for (int i = 0; i < 16; ++i) {
        if ((i & BIT) == 0) {
            const int j = i | BIT;
            const float a0r = sr[i], a0i = si[i];
            const float a1r = sr[j], a1i = si[j];
            sr[i] = fmaf(c, a0r,  s * a1i);
            si[i] = fmaf(c, a0i, -s * a1r);
            sr[j] = fmaf(c, a1r,  s * a0i);
            si[j] = fmaf(c, a1i, -s * a0r);
        }
    }
}

template<int CB, int TB>
__device__ __forceinline__ void apply_cnot(float* sr, float* si)
{
    #pragma unroll
    for (int i = 0; i < 16; ++i) {
        if ((i & CB) && !(i & TB)) {
            const int j = i | TB;
            float tr = sr[i]; sr[i] = sr[j]; sr[j] = tr;
            float ti = si[i]; si[i] = si[j]; si[j] = ti;
        }
    }
}

__global__ __launch_bounds__(BLOCK, 4)
void fused_hybrid(const float* __restrict__ x,   // [B, 512]
                  const float* __restrict__ W1,  // [4, 512]
                  const float* __restrict__ b1,  // [4]
                  const float* __restrict__ qp,  // [L, 4]
                  const float* __restrict__ W2,  // [1, 4]
                  const float* __restrict__ b2,  // [1]
                  float* __restrict__ out,       // [B, 1]
                  int B, int L)
{
    __shared__ float tile[ROWS * LSTR];
    const int t    = threadIdx.x;
    const int row0 = blockIdx.x * ROWS;

    float acc0 = 0.f, acc1 = 0.f, acc2 = 0.f, acc3 = 0.f;

    const float4* __restrict__ xv = reinterpret_cast<const float4*>(x);

    for (int ch = 0; ch < NCH; ++ch) {
        // ---- stage [256 rows x 32 cols] fp32 into LDS, coalesced ----
        #pragma unroll
        for (int k = 0; k < (ROWS * CHUNK / 4) / BLOCK; ++k) {   // 8 float4/thread
            const int f   = k * BLOCK + t;     // 0..2047 flat float4 index
            const int r   = f >> 3;            // tile row
            const int c4  = f & 7;             // float4 column within chunk
            int grow = row0 + r;
            if (grow >= B) grow = B - 1;       // clamp (B divisible by 256 anyway)
            const float4 v = xv[(size_t)grow * (D / 4) + ch * (CHUNK / 4) + c4];
            *reinterpret_cast<float4*>(&tile[r * LSTR + c4 * 4]) = v;
        }
        __syncthreads();

        // ---- each thread: 32 elements of its row x 4 weight rows ----
        #pragma unroll
        for (int c4 = 0; c4 < CHUNK / 4; ++c4) {
            const float4 v = *reinterpret_cast<const float4*>(&tile[t * LSTR + c4 * 4]);
            const int wb = ch * CHUNK + c4 * 4;          // wave-uniform -> s_load
            const float4 w0 = *reinterpret_cast<const float4*>(&W1[0 * D + wb]);
            const float4 w1 = *reinterpret_cast<const float4*>(&W1[1 * D + wb]);
            const float4 w2 = *reinterpret_cast<const float4*>(&W1[2 * D + wb]);
            const float4 w3 = *reinterpret_cast<const float4*>(&W1[3 * D + wb]);
            acc0 = fmaf(v.x, w0.x, fmaf(v.y, w0.y, fmaf(v.z, w0.z, fmaf(v.w, w0.w, acc0))));
            acc1 = fmaf(v.x, w1.x, fmaf(v.y, w1.y, fmaf(v.z, w1.z, fmaf(v.w, w1.w, acc1))));
            acc2 = fmaf(v.x, w2.x, fmaf(v.y, w2.y, fmaf(v.z, w2.z, fmaf(v.w, w2.w, acc2))));
            acc3 = fmaf(v.x, w3.x, fmaf(v.y, w3.y, fmaf(v.z, w3.z, fmaf(v.w, w3.w, acc3))));
        }
        __syncthreads();
    }

    // ---- bias + ReLU -> angles ----
    const float h0 = fmaxf(acc0 + b1[0], 0.f);
    const float h1 = fmaxf(acc1 + b1[1], 0.f);
    const float h2 = fmaxf(acc2 + b1[2], 0.f);
    const float h3 = fmaxf(acc3 + b1[3], 0.f);

    // ---- 4-qubit statevector sim, fully in registers ----
    float sr[16], si[16];
    #pragma unroll
    for (int i = 0; i < 16; ++i) { sr[i] = 0.f; si[i] = 0.f; }
    sr[0] = 1.f;

    // AngleEmbedding: RX(h[w]) on wire w (wire 0 = bit 8 ... wire 3 = bit 1)
    apply_rx<8>(sr, si, h0);
    apply_rx<4>(sr, si, h1);
    apply_rx<2>(sr, si, h2);
    apply_rx<1>(sr, si, h3);

    // BasicEntanglerLayers
    for (int l = 0; l < L; ++l) {
        apply_rx<8>(sr, si, qp[l * 4 + 0]);
        apply_rx<4>(sr, si, qp[l * 4 + 1]);
        apply_rx<2>(sr, si, qp[l * 4 + 2]);
        apply_rx<1>(sr, si, qp[l * 4 + 3]);
        apply_cnot<8, 4>(sr, si);   // CNOT(0,1)
        apply_cnot<4, 2>(sr, si);   // CNOT(1,2)
        apply_cnot<2, 1>(sr, si);   // CNOT(2,3)
        apply_cnot<1, 8>(sr, si);   // CNOT(3,0)
    }

    // ---- <Z_w> then linear head ----
    float z0 = 0.f, z1 = 0.f, z2 = 0.f, z3 = 0.f;
    #pragma unroll
    for (int i = 0; i < 16; ++i) {
        const float p = fmaf(sr[i], sr[i], si[i] * si[i]);
        z0 += (i & 8) ? -p : p;
        z1 += (i & 4) ? -p : p;
        z2 += (i & 2) ? -p : p;
        z3 += (i & 1) ? -p : p;
    }
    const float o = fmaf(z0, W2[0], fmaf(z1, W2[1], fmaf(z2, W2[2], fmaf(z3, W2[3], b2[0]))));

    const int myrow = row0 + t;
    if (myrow < B) out[myrow] = o;
}

extern "C" void kernel_launch(void* const* d_in, const int* in_sizes, int n_in,
                              void* d_out, int out_size, void* d_ws, size_t ws_size,
                              hipStream_t stream)
{
    const float* x  = (const float*)d_in[0];
    const float* W1 = (const float*)d_in[1];
    const float* b1 = (const float*)d_in[2];
    const float* qp = (const float*)d_in[3];
    const float* W2 = (const float*)d_in[4];
    const float* b2 = (const float*)d_in[5];
    float* out = (float*)d_out;

    const int B = in_sizes[0] / D;       // 262144
    const int L = in_sizes[3] / 4;       // 3 entangler layers

    const int grid = (B + ROWS - 1) / ROWS;   // 1024 blocks
    fused_hybrid<<<grid, BLOCK, 0, stream>>>(x, W1, b1, qp, W2, b2, out, B, L);
}

// Round 2
// 681.913 us; speedup vs baseline: 1.0196x; 1.0196x over previous
//
#include <hip/hip_runtime.h>

constexpr int BLOCK = 256;          // 4 waves
constexpr int ROWS  = 256;          // rows per block (1 per thread in phase B)
constexpr int D     = 512;          // inner dim
constexpr int DV    = D / 4;        // 128 float4 per row

// ---- 4-qubit state helpers (qubit 0 = MSB of 4-bit index, per jax reshape) ----

template<int BIT>
__device__ __forceinline__ void apply_rx(float* sr, float* si, float theta)
{
    float s, c;
    __sincosf(0.5f * theta, &s, &c);
    // gate [[c, -i s],[-i s, c]]
    #pragma unroll
    for (int i = 0; i < 16; ++i) {
        if ((i & BIT) == 0) {
            const int j = i | BIT;
            const float a0r = sr[i], a0i = si[i];
            const float a1r = sr[j], a1i = si[j];
            sr[i] = fmaf(c, a0r,  s * a1i);
            si[i] = fmaf(c, a0i, -s * a1r);
            sr[j] = fmaf(c, a1r,  s * a0i);
            si[j] = fmaf(c, a1i, -s * a0r);
        }
    }
}

template<int CB, int TB>
__device__ __forceinline__ void apply_cnot(float* sr, float* si)
{
    #pragma unroll
    for (int i = 0; i < 16; ++i) {
        if ((i & CB) && !(i & TB)) {
            const int j = i | TB;
            float tr = sr[i]; sr[i] = sr[j]; sr[j] = tr;
            float ti = si[i]; si[i] = si[j]; si[j] = ti;
        }
    }
}

__global__ __launch_bounds__(BLOCK, 4)
void fused_hybrid(const float* __restrict__ x,   // [B, 512]
                  const float* __restrict__ W1,  // [4, 512]
                  const float* __restrict__ b1,  // [4]
                  const float* __restrict__ qp,  // [L, 4]
                  const float* __restrict__ W2,  // [1, 4]
                  const float* __restrict__ b2,  // [1]
                  float* __restrict__ out,       // [B, 1]
                  int B, int L)
{
    __shared__ float4 hbuf[ROWS];    // 4 KB handoff: h[0..3] per row

    const int t    = threadIdx.x;
    const int l    = t & 63;         // lane
    const int wv   = t >> 6;         // wave 0..3
    const int c    = l & 31;         // column-group within row (float4 index base)
    const int half = l >> 5;         // which of the 2 rows this iteration
    const int row0 = blockIdx.x * ROWS;

    const float4* __restrict__ xv  = reinterpret_cast<const float4*>(x);
    const float4* __restrict__ w1v = reinterpret_cast<const float4*>(W1);

    // ---- phase A: streaming GEMV, no barriers in hot loop ----
    // W1 fragment in registers: w1f[wr][s] = W1[wr] float4 at index s*32 + c
    float4 w1f[4][4];
    #pragma unroll
    for (int wr = 0; wr < 4; ++wr)
        #pragma unroll
        for (int s = 0; s < 4; ++s)
            w1f[wr][s] = w1v[wr * DV + s * 32 + c];

    // wave wv owns rows [wv*64, wv*64+64) of this block; 2 rows per iteration
    int rb = wv * 64 + half;                        // rowInBlock for it=0
    const float4* xrow = xv + (size_t)(row0 + rb) * DV + c;

    float4 xa[4];
    #pragma unroll
    for (int s = 0; s < 4; ++s) xa[s] = xrow[s * 32];

    for (int it = 0; it < 32; ++it) {
        // prefetch next iteration's row data (2 rows ahead)
        float4 xb[4];
        if (it < 31) {
            const float4* nx = xrow + 2 * DV;
            #pragma unroll
            for (int s = 0; s < 4; ++s) xb[s] = nx[s * 32];
        }

        float a0 = 0.f, a1 = 0.f, a2 = 0.f, a3 = 0.f;
        #pragma unroll
        for (int s = 0; s < 4; ++s) {
            const float4 v = xa[s];
            a0 = fmaf(v.x, w1f[0][s].x, fmaf(v.y, w1f[0][s].y, fmaf(v.z, w1f[0][s].z, fmaf(v.w, w1f[0][s].w, a0))));
            a1 = fmaf(v.x, w1f[1][s].x, fmaf(v.y, w1f[1][s].y, fmaf(v.z, w1f[1][s].z, fmaf(v.w, w1f[1][s].w, a1))));
            a2 = fmaf(v.x, w1f[2][s].x, fmaf(v.y, w1f[2][s].y, fmaf(v.z, w1f[2][s].z, fmaf(v.w, w1f[2][s].w, a2))));
            a3 = fmaf(v.x, w1f[3][s].x, fmaf(v.y, w1f[3][s].y, fmaf(v.z, w1f[3][s].z, fmaf(v.w, w1f[3][s].w, a3))));
        }

        // butterfly reduce within each 32-lane half (masks < 32 stay in-half)
        #pragma unroll
        for (int m = 1; m < 32; m <<= 1) {
            a0 += __shfl_xor(a0, m, 64);
            a1 += __shfl_xor(a1, m, 64);
            a2 += __shfl_xor(a2, m, 64);
            a3 += __shfl_xor(a3, m, 64);
        }

        if (c == 0) hbuf[wv * 64 + it * 2 + half] = make_float4(a0, a1, a2, a3);

        xrow += 2 * DV;
        #pragma unroll
        for (int s = 0; s < 4; ++s) xa[s] = xb[s];
    }

    __syncthreads();

    // ---- phase B: thread t owns row row0+t ----
    const float4 h4 = hbuf[t];
    const float h0 = fmaxf(h4.x + b1[0], 0.f);
    const float h1 = fmaxf(h4.y + b1[1], 0.f);
    const float h2 = fmaxf(h4.z + b1[2], 0.f);
    const float h3 = fmaxf(h4.w + b1[3], 0.f);

    // 4-qubit statevector sim, fully in registers
    float sr[16], si[16];
    #pragma unroll
    for (int i = 0; i < 16; ++i) { sr[i] = 0.f; si[i] = 0.f; }
    sr[0] = 1.f;

    // AngleEmbedding: RX(h[w]) on wire w (wire 0 = bit 8 ... wire 3 = bit 1)
    apply_rx<8>(sr, si, h0);
    apply_rx<4>(sr, si, h1);
    apply_rx<2>(sr, si, h2);
    apply_rx<1>(sr, si, h3);

    // BasicEntanglerLayers
    for (int lay = 0; lay < L; ++lay) {
        apply_rx<8>(sr, si, qp[lay * 4 + 0]);
        apply_rx<4>(sr, si, qp[lay * 4 + 1]);
        apply_rx<2>(sr, si, qp[lay * 4 + 2]);
        apply_rx<1>(sr, si, qp[lay * 4 + 3]);
        apply_cnot<8, 4>(sr, si);   // CNOT(0,1)
        apply_cnot<4, 2>(sr, si);   // CNOT(1,2)
        apply_cnot<2, 1>(sr, si);   // CNOT(2,3)
        apply_cnot<1, 8>(sr, si);   // CNOT(3,0)
    }

    // <Z_w> then linear head
    float z0 = 0.f, z1 = 0.f, z2 = 0.f, z3 = 0.f;
    #pragma unroll
    for (int i = 0; i < 16; ++i) {
        const float p = fmaf(sr[i], sr[i], si[i] * si[i]);
        z0 += (i & 8) ? -p : p;
        z1 += (i & 4) ? -p : p;
        z2 += (i & 2) ? -p : p;
        z3 += (i & 1) ? -p : p;
    }
    const float o = fmaf(z0, W2[0], fmaf(z1, W2[1], fmaf(z2, W2[2], fmaf(z3, W2[3], b2[0]))));

    const int myrow = row0 + t;
    if (myrow < B) out[myrow] = o;
}

extern "C" void kernel_launch(void* const* d_in, const int* in_sizes, int n_in,
                              void* d_out, int out_size, void* d_ws, size_t ws_size,
                              hipStream_t stream)
{
    const float* x  = (const float*)d_in[0];
    const float* W1 = (const float*)d_in[1];
    const float* b1 = (const float*)d_in[2];
    const float* qp = (const float*)d_in[3];
    const float* W2 = (const float*)d_in[4];
    const float* b2 = (const float*)d_in[5];
    float* out = (float*)d_out;

    const int B = in_sizes[0] / D;       // 262144
    const int L = in_sizes[3] / 4;       // 3 entangler layers

    const int grid = (B + ROWS - 1) / ROWS;   // 1024 blocks
    fused_hybrid<<<grid, BLOCK, 0, stream>>>(x, W1, b1, qp, W2, b2, out, B, L);
}

// Round 4
// 658.594 us; speedup vs baseline: 1.0557x; 1.0354x over previous
//
#include <hip/hip_runtime.h>

constexpr int BLOCK = 256;          // 4 waves
constexpr int ROWS  = 256;          // rows per block (1 per thread in phase B)
constexpr int D     = 512;          // inner dim
constexpr int DV    = D / 4;        // 128 float4 per row

typedef float fx4 __attribute__((ext_vector_type(4)));   // native vec for nt-load

__device__ __forceinline__ fx4 nt_load4(const float4* p)
{
    return __builtin_nontemporal_load(reinterpret_cast<const fx4*>(p));
}

// ---- 4-qubit state helpers (qubit 0 = MSB of 4-bit index, per jax reshape) ----

template<int BIT>
__device__ __forceinline__ void apply_rx(float* sr, float* si, float theta)
{
    float s, c;
    __sincosf(0.5f * theta, &s, &c);
    // gate [[c, -i s],[-i s, c]]
    #pragma unroll
    for (int i = 0; i < 16; ++i) {
        if ((i & BIT) == 0) {
            const int j = i | BIT;
            const float a0r = sr[i], a0i = si[i];
            const float a1r = sr[j], a1i = si[j];
            sr[i] = fmaf(c, a0r,  s * a1i);
            si[i] = fmaf(c, a0i, -s * a1r);
            sr[j] = fmaf(c, a1r,  s * a0i);
            si[j] = fmaf(c, a1i, -s * a0r);
        }
    }
}

template<int CB, int TB>
__device__ __forceinline__ void apply_cnot(float* sr, float* si)
{
    #pragma unroll
    for (int i = 0; i < 16; ++i) {
        if ((i & CB) && !(i & TB)) {
            const int j = i | TB;
            float tr = sr[i]; sr[i] = sr[j]; sr[j] = tr;
            float ti = si[i]; si[i] = si[j]; si[j] = ti;
        }
    }
}

__global__ __launch_bounds__(BLOCK, 4)
void fused_hybrid(const float* __restrict__ x,   // [B, 512]
                  const float* __restrict__ W1,  // [4, 512]
                  const float* __restrict__ b1,  // [4]
                  const float* __restrict__ qp,  // [L, 4]
                  const float* __restrict__ W2,  // [1, 4]
                  const float* __restrict__ b2,  // [1]
                  float* __restrict__ out,       // [B, 1]
                  int B, int L)
{
    __shared__ alignas(16) float hbuf[ROWS * 4];   // 4 KB handoff: h[0..3] per row

    const int t    = threadIdx.x;
    const int l    = t & 63;         // lane
    const int wv   = t >> 6;         // wave 0..3
    const int c    = l & 31;         // column-group within row (float4 index base)
    const int half = l >> 5;         // which of the 2 rows this iteration
    const int row0 = blockIdx.x * ROWS;

    const float4* __restrict__ xv  = reinterpret_cast<const float4*>(x);
    const float4* __restrict__ w1v = reinterpret_cast<const float4*>(W1);

    // ---- phase A: streaming GEMV, barrier-free, 2-deep prefetch ----
    // W1 fragment in registers: w1f[wr][s] = W1[wr] float4 at index s*32 + c
    fx4 w1f[4][4];
    #pragma unroll
    for (int wr = 0; wr < 4; ++wr)
        #pragma unroll
        for (int s = 0; s < 4; ++s)
            w1f[wr][s] = *reinterpret_cast<const fx4*>(&w1v[wr * DV + s * 32 + c]);

    // wave wv owns rows [wv*64, wv*64+64) of this block; 2 rows per iteration
    const float4* xbase = xv + (size_t)(row0 + wv * 64 + half) * DV + c;

    fx4 buf[2][4];
    #pragma unroll
    for (int s = 0; s < 4; ++s) buf[0][s] = nt_load4(xbase + 0 * 2 * DV + s * 32);
    #pragma unroll
    for (int s = 0; s < 4; ++s) buf[1][s] = nt_load4(xbase + 1 * 2 * DV + s * 32);

    #pragma unroll 2
    for (int it = 0; it < 32; ++it) {
        const int p = it & 1;

        float a0 = 0.f, a1 = 0.f, a2 = 0.f, a3 = 0.f;
        #pragma unroll
        for (int s = 0; s < 4; ++s) {
            const fx4 v = buf[p][s];
            a0 = fmaf(v.x, w1f[0][s].x, fmaf(v.y, w1f[0][s].y, fmaf(v.z, w1f[0][s].z, fmaf(v.w, w1f[0][s].w, a0))));
            a1 = fmaf(v.x, w1f[1][s].x, fmaf(v.y, w1f[1][s].y, fmaf(v.z, w1f[1][s].z, fmaf(v.w, w1f[1][s].w, a1))));
            a2 = fmaf(v.x, w1f[2][s].x, fmaf(v.y, w1f[2][s].y, fmaf(v.z, w1f[2][s].z, fmaf(v.w, w1f[2][s].w, a2))));
            a3 = fmaf(v.x, w1f[3][s].x, fmaf(v.y, w1f[3][s].y, fmaf(v.z, w1f[3][s].z, fmaf(v.w, w1f[3][s].w, a3))));
        }

        // prefetch iteration it+2 into the buffer slot just consumed
        if (it + 2 < 32) {
            const float4* nx = xbase + (size_t)(it + 2) * 2 * DV;
            #pragma unroll
            for (int s = 0; s < 4; ++s) buf[p][s] = nt_load4(nx + s * 32);
        }

        // ---- packed transpose-reduction: 7 shfls instead of 20 ----
        // level 1 (mask 1): fold a0/a1 and a2/a3 by lane parity
        float s01 = (c & 1) ? a1 : a0;
        float d01 = (c & 1) ? a0 : a1;
        s01 += __shfl_xor(d01, 1, 64);
        float s23 = (c & 1) ? a3 : a2;
        float d23 = (c & 1) ? a2 : a3;
        s23 += __shfl_xor(d23, 1, 64);
        // level 2 (mask 2): fold s01/s23
        float sv = (c & 2) ? s23 : s01;
        float dv = (c & 2) ? s01 : s23;
        sv += __shfl_xor(dv, 2, 64);
        // now lane class (c&3)==k holds acc_k partial (4 lanes folded)
        sv += __shfl_xor(sv, 4, 64);
        sv += __shfl_xor(sv, 8, 64);
        sv += __shfl_xor(sv, 16, 64);
        // lanes c<4 hold h-component (c&3) for row (it*2+half)

        if (c < 4) hbuf[(wv * 64 + it * 2 + half) * 4 + c] = sv;
    }

    __syncthreads();

    // ---- phase B: thread t owns row row0+t ----
    const float4 h4 = *reinterpret_cast<const float4*>(&hbuf[t * 4]);
    const float h0 = fmaxf(h4.x + b1[0], 0.f);
    const float h1 = fmaxf(h4.y + b1[1], 0.f);
    const float h2 = fmaxf(h4.z + b1[2], 0.f);
    const float h3 = fmaxf(h4.w + b1[3], 0.f);

    // 4-qubit statevector sim, fully in registers
    float sr[16], si[16];
    #pragma unroll
    for (int i = 0; i < 16; ++i) { sr[i] = 0.f; si[i] = 0.f; }
    sr[0] = 1.f;

    // AngleEmbedding: RX(h[w]) on wire w (wire 0 = bit 8 ... wire 3 = bit 1)
    apply_rx<8>(sr, si, h0);
    apply_rx<4>(sr, si, h1);
    apply_rx<2>(sr, si, h2);
    apply_rx<1>(sr, si, h3);

    // BasicEntanglerLayers
    for (int lay = 0; lay < L; ++lay) {
        apply_rx<8>(sr, si, qp[lay * 4 + 0]);
        apply_rx<4>(sr, si, qp[lay * 4 + 1]);
        apply_rx<2>(sr, si, qp[lay * 4 + 2]);
        apply_rx<1>(sr, si, qp[lay * 4 + 3]);
        apply_cnot<8, 4>(sr, si);   // CNOT(0,1)
        apply_cnot<4, 2>(sr, si);   // CNOT(1,2)
        apply_cnot<2, 1>(sr, si);   // CNOT(2,3)
        apply_cnot<1, 8>(sr, si);   // CNOT(3,0)
    }

    // <Z_w> then linear head
    float z0 = 0.f, z1 = 0.f, z2 = 0.f, z3 = 0.f;
    #pragma unroll
    for (int i = 0; i < 16; ++i) {
        const float p = fmaf(sr[i], sr[i], si[i] * si[i]);
        z0 += (i & 8) ? -p : p;
        z1 += (i & 4) ? -p : p;
        z2 += (i & 2) ? -p : p;
        z3 += (i & 1) ? -p : p;
    }
    const float o = fmaf(z0, W2[0], fmaf(z1, W2[1], fmaf(z2, W2[2], fmaf(z3, W2[3], b2[0]))));

    const int myrow = row0 + t;
    if (myrow < B) out[myrow] = o;
}

extern "C" void kernel_launch(void* const* d_in, const int* in_sizes, int n_in,
                              void* d_out, int out_size, void* d_ws, size_t ws_size,
                              hipStream_t stream)
{
    const float* x  = (const float*)d_in[0];
    const float* W1 = (const float*)d_in[1];
    const float* b1 = (const float*)d_in[2];
    const float* qp = (const float*)d_in[3];
    const float* W2 = (const float*)d_in[4];
    const float* b2 = (const float*)d_in[5];
    float* out = (float*)d_out;

    const int B = in_sizes[0] / D;       // 262144
    const int L = in_sizes[3] / 4;       // 3 entangler layers

    const int grid = (B + ROWS - 1) / ROWS;   // 1024 blocks
    fused_hybrid<<<grid, BLOCK, 0, stream>>>(x, W1, b1, qp, W2, b2, out, B, L);
}